// Round 1
// baseline (510.686 us; speedup 1.0000x reference)
//
#include <hip/hip_runtime.h>
#include <hip/hip_bf16.h>
#include <math.h>

// Problem constants (fixed by reference setup_inputs)
#define BHALF 4096          // B
#define NROW 8192           // 2B
#define DIM 128             // D
#define INV_T 10.0f         // 1/temperature
#define LDP 129             // LDS padded stride (floats): A-read 4 banks, B-read 2-way (free)

// ---------------------------------------------------------------------------
// Kernel 1: row-normalize concat(view1, view2) -> e (NROW x DIM), zero expsum
// One wave (64 lanes) per row; each lane owns 2 consecutive floats.
// ---------------------------------------------------------------------------
__global__ __launch_bounds__(256) void normalize_kernel(
    const float* __restrict__ v1, const float* __restrict__ v2,
    float* __restrict__ e, float* __restrict__ expsum) {
  int row  = blockIdx.x * 4 + (threadIdx.x >> 6);
  int lane = threadIdx.x & 63;
  const float* src = (row < BHALF) ? (v1 + (size_t)row * DIM)
                                   : (v2 + (size_t)(row - BHALF) * DIM);
  float2 x = ((const float2*)src)[lane];
  float ss = x.x * x.x + x.y * x.y;
#pragma unroll
  for (int off = 32; off > 0; off >>= 1) ss += __shfl_down(ss, off);
  ss = __shfl(ss, 0);
  float nrm = fmaxf(sqrtf(ss), 1e-8f);
  float s = 1.0f / nrm;
  float2 y; y.x = x.x * s; y.y = x.y * s;
  ((float2*)(e + (size_t)row * DIM))[lane] = y;
  if (lane == 0) expsum[row] = 0.0f;
}

// ---------------------------------------------------------------------------
// Kernel 2: tiled sim + online exp-sum.
// Block: 256 threads as 16x16; tile = 64 rows x 64 cols, 4x4 per thread.
// gridDim = (128 row-tiles, 2 col-halves). Each block scans 4096 cols.
// S_i (partial) accumulated in registers, one atomicAdd per row at the end.
// pos_i written by the unique thread that computes (i, partner(i)).
// ---------------------------------------------------------------------------
__global__ __launch_bounds__(256) void sim_kernel(
    const float* __restrict__ e, float* __restrict__ expsum,
    float* __restrict__ posv) {
  __shared__ float As[64 * LDP];
  __shared__ float Bs[64 * LDP];

  const int tid = threadIdx.x;
  const int tx = tid & 15;        // col group
  const int ty = tid >> 4;        // row group
  const int rowBase  = blockIdx.x * 64;
  const int colStart = blockIdx.y * (NROW / 2);   // 0 or 4096

  // Load A tile (64 rows x 128) once, coalesced float4.
#pragma unroll
  for (int u = 0; u < 8; ++u) {
    int idx = tid + 256 * u;             // 0..2047 float4 slots
    int r   = idx >> 5;                  // /32 (32 float4 per row)
    int c4  = (idx & 31) * 4;
    float4 v = *(const float4*)(e + (size_t)(rowBase + r) * DIM + c4);
    As[r * LDP + c4 + 0] = v.x;
    As[r * LDP + c4 + 1] = v.y;
    As[r * LDP + c4 + 2] = v.z;
    As[r * LDP + c4 + 3] = v.w;
  }

  float esum[4] = {0.f, 0.f, 0.f, 0.f};
  float posHit[4] = {0.f, 0.f, 0.f, 0.f};
  int   hasPos[4] = {0, 0, 0, 0};

  for (int chunk = 0; chunk < 64; ++chunk) {
    int colTile = colStart + chunk * 64;
    __syncthreads();   // Bs safe to overwrite (and As visible on first iter)
#pragma unroll
    for (int u = 0; u < 8; ++u) {
      int idx = tid + 256 * u;
      int r   = idx >> 5;
      int c4  = (idx & 31) * 4;
      float4 v = *(const float4*)(e + (size_t)(colTile + r) * DIM + c4);
      Bs[r * LDP + c4 + 0] = v.x;
      Bs[r * LDP + c4 + 1] = v.y;
      Bs[r * LDP + c4 + 2] = v.z;
      Bs[r * LDP + c4 + 3] = v.w;
    }
    __syncthreads();

    float acc[4][4] = {{0.f}};
#pragma unroll 4
    for (int k = 0; k < DIM; ++k) {
      float a[4], b[4];
#pragma unroll
      for (int i = 0; i < 4; ++i) a[i] = As[(ty * 4 + i) * LDP + k];
#pragma unroll
      for (int j = 0; j < 4; ++j) b[j] = Bs[(tx * 4 + j) * LDP + k];
#pragma unroll
      for (int i = 0; i < 4; ++i)
#pragma unroll
        for (int j = 0; j < 4; ++j) acc[i][j] = fmaf(a[i], b[j], acc[i][j]);
    }

#pragma unroll
    for (int i = 0; i < 4; ++i) {
      int row = rowBase + ty * 4 + i;
      int partner = (row < BHALF) ? (row + BHALF) : (row - BHALF);
#pragma unroll
      for (int j = 0; j < 4; ++j) {
        int col = colTile + tx * 4 + j;
        if (col == row) continue;                 // diagonal masked (-inf)
        float ex = __expf((acc[i][j] - 1.0f) * INV_T);
        esum[i] += ex;
        if (col == partner) {                     // positive: counted again (col 0)
          esum[i] += ex;
          posHit[i] = acc[i][j];
          hasPos[i] = 1;
        }
      }
    }
  }

  // Reduce esum across the 16 col-threads sharing each row (within-wave).
#pragma unroll
  for (int i = 0; i < 4; ++i) {
    float v = esum[i];
#pragma unroll
    for (int m = 1; m < 16; m <<= 1) v += __shfl_xor(v, m);
    int row = rowBase + ty * 4 + i;
    if (tx == 0) atomicAdd(&expsum[row], v);
    if (hasPos[i]) posv[row] = posHit[i];   // unique writer across whole grid
  }
}

// ---------------------------------------------------------------------------
// Kernel 3: loss_i = log(S_i) + (1 - pos_i)/T ; out = mean(loss)
// ---------------------------------------------------------------------------
__global__ __launch_bounds__(256) void finalize_kernel(
    const float* __restrict__ expsum, const float* __restrict__ posv,
    float* __restrict__ out) {
  __shared__ float red[4];
  int tid = threadIdx.x;
  float lsum = 0.0f;
  for (int i = tid; i < NROW; i += 256) {
    float S = expsum[i];
    float p = posv[i];
    lsum += logf(S) + (1.0f - p) * INV_T;
  }
#pragma unroll
  for (int off = 32; off > 0; off >>= 1) lsum += __shfl_down(lsum, off);
  if ((tid & 63) == 0) red[tid >> 6] = lsum;
  __syncthreads();
  if (tid == 0) out[0] = (red[0] + red[1] + red[2] + red[3]) * (1.0f / NROW);
}

// ---------------------------------------------------------------------------
extern "C" void kernel_launch(void* const* d_in, const int* in_sizes, int n_in,
                              void* d_out, int out_size, void* d_ws, size_t ws_size,
                              hipStream_t stream) {
  const float* v1 = (const float*)d_in[0];
  const float* v2 = (const float*)d_in[1];
  float* out = (float*)d_out;

  float* e      = (float*)d_ws;                 // NROW*DIM floats (4 MB)
  float* expsum = e + (size_t)NROW * DIM;       // NROW floats
  float* posv   = expsum + NROW;                // NROW floats

  normalize_kernel<<<NROW / 4, 256, 0, stream>>>(v1, v2, e, expsum);
  dim3 grid(NROW / 64, 2);
  sim_kernel<<<grid, 256, 0, stream>>>(e, expsum, posv);
  finalize_kernel<<<1, 256, 0, stream>>>(expsum, posv, out);
}

// Round 2
// 119.711 us; speedup vs baseline: 4.2660x; 4.2660x over previous
//
#include <hip/hip_runtime.h>
#include <hip/hip_bf16.h>
#include <math.h>

// Problem constants (fixed by reference setup_inputs)
#define BHALF 4096          // B
#define NROW 8192           // 2B
#define DIM 128             // D
#define INV_T 10.0f         // 1/temperature

// MFMA fragment types (per guide §3, compile-verified types on gfx950)
typedef short bf16x8 __attribute__((ext_vector_type(8)));   // 8 bf16 = 4 VGPRs
typedef float f32x4  __attribute__((ext_vector_type(4)));   // C/D frag

// ---------------------------------------------------------------------------
// Kernel 1: row-normalize concat(view1, view2) -> e_bf16 (NROW x DIM),
// zero expsum. One wave per row; each lane owns 2 consecutive floats.
// ---------------------------------------------------------------------------
__global__ __launch_bounds__(256) void normalize_kernel(
    const float* __restrict__ v1, const float* __restrict__ v2,
    __hip_bfloat16* __restrict__ e, float* __restrict__ expsum) {
  int row  = blockIdx.x * 4 + (threadIdx.x >> 6);
  int lane = threadIdx.x & 63;
  const float* src = (row < BHALF) ? (v1 + (size_t)row * DIM)
                                   : (v2 + (size_t)(row - BHALF) * DIM);
  float2 x = ((const float2*)src)[lane];
  float ss = x.x * x.x + x.y * x.y;
#pragma unroll
  for (int off = 32; off > 0; off >>= 1) ss += __shfl_down(ss, off);
  ss = __shfl(ss, 0);
  float s = 1.0f / fmaxf(sqrtf(ss), 1e-8f);
  float2 y; y.x = x.x * s; y.y = x.y * s;
  ((__hip_bfloat162*)(e + (size_t)row * DIM))[lane] =
      __float22bfloat162_rn(make_float2(y.x, y.y));
  if (lane == 0) expsum[row] = 0.0f;
}

// ---------------------------------------------------------------------------
// Kernel 2: MFMA sim + online exp-sum (sim never materialized).
// Block = 256 threads = 4 waves. Each wave: 64 rows (4 x 16-row A-frags,
// register-resident across the whole sweep). Block sweeps 512 cols in 4
// stages of 128 cols staged in LDS (shared by the 4 waves).
// Grid: (8192/256 row-blocks, 8192/512 col-splits) = 32 x 16 = 512 blocks.
// Per 16x16 subtile: 4 ds_read_b128 (B-frag) + 16 MFMA  -> 4:1 MFMA:LDS.
// ---------------------------------------------------------------------------
#define SCOLS 128
#define LDB 136   // LDS col stride in bf16: 272 B -> bank stride 4, 2-way max (free)

__global__ __launch_bounds__(256, 2) void sim_kernel(
    const ushort* __restrict__ e, float* __restrict__ expsum,
    float* __restrict__ posv) {
  __shared__ ushort Bs[SCOLS * LDB] __attribute__((aligned(16)));

  const int tid  = threadIdx.x;
  const int wave = tid >> 6;
  const int lane = tid & 63;
  const int n    = lane & 15;       // col within 16x16 tile (C: col=lane&15)
  const int quad = lane >> 4;       // k-quad for A/B frags; row-quad for C

  const int rowBlock    = blockIdx.x * 256;
  const int colBlock    = blockIdx.y * 512;
  const int waveRowBase = rowBlock + wave * 64;

  // A fragments: A[m=lane&15][k=quad*8+j], k-step kk covers k=kk*32+quad*8..+7.
  // 4 row-frags x 4 k-steps x 8 bf16 = 64 VGPRs, resident for the whole sweep.
  bf16x8 a_frag[4][4];
#pragma unroll
  for (int rf = 0; rf < 4; ++rf) {
    const ushort* rp = e + (size_t)(waveRowBase + rf * 16 + n) * DIM + quad * 8;
#pragma unroll
    for (int kk = 0; kk < 4; ++kk)
      a_frag[rf][kk] = *(const bf16x8*)(rp + kk * 32);
  }

  float esum[4][4];
#pragma unroll
  for (int rf = 0; rf < 4; ++rf)
#pragma unroll
    for (int r = 0; r < 4; ++r) esum[rf][r] = 0.0f;

  for (int stage = 0; stage < 4; ++stage) {
    const int colStart = colBlock + stage * SCOLS;
    __syncthreads();   // previous stage's reads done before overwrite
    // Stage 128 cols x 256 B into LDS, coalesced uint4 (16 lanes per col row).
#pragma unroll
    for (int u = 0; u < 8; ++u) {
      int idx = tid + 256 * u;      // 0..2047 uint4 slots
      int c   = idx >> 4;           // col (0..127)
      int q4  = idx & 15;           // 16B chunk within the 256B row
      uint4 v = *(const uint4*)(e + (size_t)(colStart + c) * DIM + q4 * 8);
      *(uint4*)(&Bs[c * LDB + q4 * 8]) = v;
    }
    __syncthreads();

#pragma unroll 1
    for (int sub = 0; sub < 8; ++sub) {
      // B-frag: row n of E (= col n of sim), same k layout as A (m92-verified).
      const ushort* bp = &Bs[(sub * 16 + n) * LDB + quad * 8];
      bf16x8 b_frag[4];
#pragma unroll
      for (int kk = 0; kk < 4; ++kk)
        b_frag[kk] = *(const bf16x8*)(bp + kk * 32);

      const int col = colStart + sub * 16 + n;
#pragma unroll
      for (int rf = 0; rf < 4; ++rf) {
        f32x4 acc = {0.f, 0.f, 0.f, 0.f};
#pragma unroll
        for (int kk = 0; kk < 4; ++kk)
          acc = __builtin_amdgcn_mfma_f32_16x16x32_bf16(
              a_frag[rf][kk], b_frag[kk], acc, 0, 0, 0);
        // C layout: row = quad*4 + reg, col = lane&15 (m89/m91 verified).
#pragma unroll
        for (int r = 0; r < 4; ++r) {
          int row = waveRowBase + rf * 16 + quad * 4 + r;
          float val = acc[r];
          float ex = __expf((val - 1.0f) * INV_T);   // shift: sim<=~1
          if (col != row) {                           // diagonal masked
            esum[rf][r] += ex;
            if (col == (row ^ BHALF)) {               // partner: counted twice
              esum[rf][r] += ex;                      // (col 0 + unmasked neg)
              posv[row] = val;                        // unique writer grid-wide
            }
          }
        }
      }
    }
  }

  // Reduce esum across the 16 col-lanes of each quad, one atomic per row.
#pragma unroll
  for (int rf = 0; rf < 4; ++rf)
#pragma unroll
    for (int r = 0; r < 4; ++r) {
      float v = esum[rf][r];
#pragma unroll
      for (int m = 1; m < 16; m <<= 1) v += __shfl_xor(v, m);
      if (n == 0)
        atomicAdd(&expsum[waveRowBase + rf * 16 + quad * 4 + r], v);
    }
}

// ---------------------------------------------------------------------------
// Kernel 3: loss_i = log(S_i) + (1 - pos_i)/T ; out = mean(loss)
// ---------------------------------------------------------------------------
__global__ __launch_bounds__(256) void finalize_kernel(
    const float* __restrict__ expsum, const float* __restrict__ posv,
    float* __restrict__ out) {
  __shared__ float red[4];
  int tid = threadIdx.x;
  float lsum = 0.0f;
  for (int i = tid; i < NROW; i += 256) {
    lsum += __logf(expsum[i]) + (1.0f - posv[i]) * INV_T;
  }
#pragma unroll
  for (int off = 32; off > 0; off >>= 1) lsum += __shfl_down(lsum, off);
  if ((tid & 63) == 0) red[tid >> 6] = lsum;
  __syncthreads();
  if (tid == 0) out[0] = (red[0] + red[1] + red[2] + red[3]) * (1.0f / NROW);
}

// ---------------------------------------------------------------------------
extern "C" void kernel_launch(void* const* d_in, const int* in_sizes, int n_in,
                              void* d_out, int out_size, void* d_ws, size_t ws_size,
                              hipStream_t stream) {
  const float* v1 = (const float*)d_in[0];
  const float* v2 = (const float*)d_in[1];
  float* out = (float*)d_out;

  __hip_bfloat16* e = (__hip_bfloat16*)d_ws;          // NROW*DIM bf16 (2 MB)
  float* expsum = (float*)(e + (size_t)NROW * DIM);   // NROW floats
  float* posv   = expsum + NROW;                      // NROW floats

  normalize_kernel<<<NROW / 4, 256, 0, stream>>>(v1, v2, e, expsum);
  dim3 grid(NROW / 256, NROW / 512);
  sim_kernel<<<grid, 256, 0, stream>>>((const ushort*)e, expsum, posv);
  finalize_kernel<<<1, 256, 0, stream>>>(expsum, posv, out);
}

// Round 3
// 83.064 us; speedup vs baseline: 6.1481x; 1.4412x over previous
//
#include <hip/hip_runtime.h>
#include <hip/hip_bf16.h>
#include <math.h>

// Problem constants (fixed by reference setup_inputs)
#define BHALF 4096          // B
#define NROW 8192           // 2B
#define DIM 128             // D
#define INV_T 10.0f         // 1/temperature
#define LDB 136             // LDS col stride (ushorts)

typedef short bf16x8 __attribute__((ext_vector_type(8)));   // 8 bf16 = 4 VGPRs
typedef float f32x4  __attribute__((ext_vector_type(4)));   // C/D frag

// ---------------------------------------------------------------------------
// Kernel 1: row-normalize concat(view1, view2) -> e_bf16 (NROW x DIM);
// zero expsum and d_out. One wave per row.
// ---------------------------------------------------------------------------
__global__ __launch_bounds__(256) void normalize_kernel(
    const float* __restrict__ v1, const float* __restrict__ v2,
    __hip_bfloat16* __restrict__ e, float* __restrict__ expsum,
    float* __restrict__ out) {
  int row  = blockIdx.x * 4 + (threadIdx.x >> 6);
  int lane = threadIdx.x & 63;
  const float* src = (row < BHALF) ? (v1 + (size_t)row * DIM)
                                   : (v2 + (size_t)(row - BHALF) * DIM);
  float2 x = ((const float2*)src)[lane];
  float ss = x.x * x.x + x.y * x.y;
#pragma unroll
  for (int off = 32; off > 0; off >>= 1) ss += __shfl_down(ss, off);
  ss = __shfl(ss, 0);
  float s = 1.0f / fmaxf(sqrtf(ss), 1e-8f);
  ((__hip_bfloat162*)(e + (size_t)row * DIM))[lane] =
      __float22bfloat162_rn(make_float2(x.x * s, x.y * s));
  if (lane == 0) expsum[row] = 0.0f;
  if (blockIdx.x == 0 && threadIdx.x == 0) out[0] = 0.0f;
}

// ---------------------------------------------------------------------------
// Symmetric MFMA sweep over one 128x128 tile (rows: strip r, cols: strip c).
// MODE 0: diagonal tile (r==c). Full tile, exclude col==row, row-sums only
//         (both orders of every in-strip pair are computed explicitly).
// MODE 1: normal off-diag pair. Each exp feeds row-sum AND col-sum (symmetry).
// MODE 2: partner tile (c == r^32). Like MODE 1 but local-diagonal elements
//         are positives: weight 2 (counted in denom as col-0 AND as an
//         unmasked negative) and posv[] written for BOTH partners.
// ---------------------------------------------------------------------------
template <int MODE>
__device__ __forceinline__ void sweep_tile(
    const ushort* __restrict__ Bs, const bf16x8 (&a_frag)[2][4],
    float (&rsum)[2][4], float* __restrict__ expsum,
    float* __restrict__ posv, int wave, int lane, int n, int quad,
    int rowStrip, int colStrip) {
  const int colBase = colStrip * 128;
#pragma unroll 1
  for (int sub = 0; sub < 8; ++sub) {
    const ushort* bp = &Bs[(sub * 16 + n) * LDB + quad * 8];
    bf16x8 b[4];
#pragma unroll
    for (int kk = 0; kk < 4; ++kk) b[kk] = *(const bf16x8*)(bp + kk * 32);
    float csum = 0.0f;
    const int lc = sub * 16 + n;
#pragma unroll
    for (int rf = 0; rf < 2; ++rf) {
      f32x4 acc = {0.f, 0.f, 0.f, 0.f};
#pragma unroll
      for (int kk = 0; kk < 4; ++kk)
        acc = __builtin_amdgcn_mfma_f32_16x16x32_bf16(a_frag[rf][kk], b[kk],
                                                      acc, 0, 0, 0);
      // C layout: row = quad*4 + reg, col = lane&15 (m89/m91 verified).
#pragma unroll
      for (int rr = 0; rr < 4; ++rr) {
        const int lr = wave * 32 + rf * 16 + quad * 4 + rr;
        const float val = acc[rr];
        const float ex = __expf((val - 1.0f) * INV_T);  // shift: sim <= ~1
        if (MODE == 0) {
          rsum[rf][rr] += (lr == lc) ? 0.0f : ex;       // mask true diagonal
        } else if (MODE == 1) {
          rsum[rf][rr] += ex;
          csum += ex;
        } else {                                        // partner tile
          const bool hit = (lr == lc);
          const float w = hit ? 2.0f : 1.0f;
          rsum[rf][rr] += w * ex;
          csum += w * ex;
          if (hit) {
            posv[rowStrip * 128 + lr] = val;            // row i
            posv[colBase + lc] = val;                   // partner j = i+4096
          }
        }
      }
    }
    if (MODE != 0) {
      // col-sum: reduce over this wave's 32 rows (across quads), one atomic.
      csum += __shfl_xor(csum, 16);
      csum += __shfl_xor(csum, 32);
      if (lane < 16) atomicAdd(&expsum[colBase + lc], csum);
    }
  }
}

// ---------------------------------------------------------------------------
// Kernel 2: symmetric sim + online exp-sum. Grid (64, 33): x = row strip,
// y = cyclic offset d; col strip = (r+d)&63. d=32 valid only for r<32.
// Block: 4 waves; wave w owns rows [strip*128 + w*32, +32) (A in registers),
// all 128 cols of strip c staged once in LDS.
// ---------------------------------------------------------------------------
__global__ __launch_bounds__(256, 4) void sim_kernel(
    const ushort* __restrict__ e, float* __restrict__ expsum,
    float* __restrict__ posv) {
  const int r = blockIdx.x;
  const int d = blockIdx.y;
  if (d == 32 && r >= 32) return;   // uniform: whole block exits, no barrier hazard
  const int c = (r + d) & 63;

  __shared__ ushort Bs[128 * LDB] __attribute__((aligned(16)));

  const int tid  = threadIdx.x;
  const int wave = tid >> 6;
  const int lane = tid & 63;
  const int n    = lane & 15;
  const int quad = lane >> 4;

  // Stage col strip: 128 rows of E x 256 B, coalesced uint4.
#pragma unroll
  for (int u = 0; u < 8; ++u) {
    int idx = tid + 256 * u;
    int cc  = idx >> 4;
    int q4  = idx & 15;
    *(uint4*)(&Bs[cc * LDB + q4 * 8]) =
        *(const uint4*)(e + (size_t)(c * 128 + cc) * DIM + q4 * 8);
  }

  // A fragments: 2 row-frags x 4 k-steps, register-resident.
  bf16x8 a_frag[2][4];
  const int rowWave = r * 128 + wave * 32;
#pragma unroll
  for (int rf = 0; rf < 2; ++rf) {
    const ushort* rp = e + (size_t)(rowWave + rf * 16 + n) * DIM + quad * 8;
#pragma unroll
    for (int kk = 0; kk < 4; ++kk)
      a_frag[rf][kk] = *(const bf16x8*)(rp + kk * 32);
  }

  float rsum[2][4] = {{0.f, 0.f, 0.f, 0.f}, {0.f, 0.f, 0.f, 0.f}};
  __syncthreads();

  if (d == 0)
    sweep_tile<0>(Bs, a_frag, rsum, expsum, posv, wave, lane, n, quad, r, c);
  else if (d == 32)
    sweep_tile<2>(Bs, a_frag, rsum, expsum, posv, wave, lane, n, quad, r, c);
  else
    sweep_tile<1>(Bs, a_frag, rsum, expsum, posv, wave, lane, n, quad, r, c);

  // Row sums: reduce across the 16 col-lanes, one atomic per row.
#pragma unroll
  for (int rf = 0; rf < 2; ++rf)
#pragma unroll
    for (int rr = 0; rr < 4; ++rr) {
      float v = rsum[rf][rr];
      v += __shfl_xor(v, 1);
      v += __shfl_xor(v, 2);
      v += __shfl_xor(v, 4);
      v += __shfl_xor(v, 8);
      if (n == 0) atomicAdd(&expsum[rowWave + rf * 16 + quad * 4 + rr], v);
    }
}

// ---------------------------------------------------------------------------
// Kernel 3: loss_i = log(S_i) + (1 - pos_i)/T ; out = mean (atomic partials).
// 32 blocks x 256 threads, one row per thread.
// ---------------------------------------------------------------------------
__global__ __launch_bounds__(256) void finalize_kernel(
    const float* __restrict__ expsum, const float* __restrict__ posv,
    float* __restrict__ out) {
  __shared__ float red[4];
  const int i = blockIdx.x * 256 + threadIdx.x;
  float l = __logf(expsum[i]) + (1.0f - posv[i]) * INV_T;
#pragma unroll
  for (int off = 32; off > 0; off >>= 1) l += __shfl_down(l, off);
  if ((threadIdx.x & 63) == 0) red[threadIdx.x >> 6] = l;
  __syncthreads();
  if (threadIdx.x == 0)
    atomicAdd(out, (red[0] + red[1] + red[2] + red[3]) * (1.0f / NROW));
}

// ---------------------------------------------------------------------------
extern "C" void kernel_launch(void* const* d_in, const int* in_sizes, int n_in,
                              void* d_out, int out_size, void* d_ws, size_t ws_size,
                              hipStream_t stream) {
  const float* v1 = (const float*)d_in[0];
  const float* v2 = (const float*)d_in[1];
  float* out = (float*)d_out;

  __hip_bfloat16* e = (__hip_bfloat16*)d_ws;          // NROW*DIM bf16 (2 MB)
  float* expsum = (float*)(e + (size_t)NROW * DIM);   // NROW floats
  float* posv   = expsum + NROW;                      // NROW floats

  normalize_kernel<<<NROW / 4, 256, 0, stream>>>(v1, v2, e, expsum, out);
  dim3 grid(64, 33);
  sim_kernel<<<grid, 256, 0, stream>>>((const ushort*)e, expsum, posv);
  finalize_kernel<<<32, 256, 0, stream>>>(expsum, posv, out);
}